// Round 1
// baseline (789.823 us; speedup 1.0000x reference)
//
#include <hip/hip_runtime.h>

#define DIMN 2048
#define RANKN 128
#define TT 1024
#define BBATCH 16
#define BD (BBATCH * DIMN)   // 32768 elements per timestep slice

typedef __attribute__((ext_vector_type(4))) float floatx4;
typedef __attribute__((ext_vector_type(8))) short short8;

// fp32 -> bf16 round-to-nearest-even on raw bits
__device__ __forceinline__ short f2bf(float f) {
    unsigned u = __float_as_uint(f);
    unsigned r = (u + 0x7FFFu + ((u >> 16) & 1u)) >> 16;
    return (short)r;
}

__device__ __forceinline__ float fast_sigmoid(float z) {
    return 1.0f / (1.0f + __expf(-z));
}
__device__ __forceinline__ float fast_tanh(float z) {
    return 1.0f - 2.0f / (__expf(2.0f * z) + 1.0f);
}

// ---------------------------------------------------------------------------
// Phase 1: xv = x @ V_x^T, xd = x @ V_d^T in ONE pass over x (x read once
// from HBM, V tiles are L2-resident). M-tile 64 -> 256 blocks (1/CU).
// Output bf16 [16384][256] = xv | xd. This is the same rounding point the
// old phase-2 staging applied (f2bf of the fp32 accumulator), so downstream
// numerics are bit-identical.
// 4 waves arranged 2x2: wm in {0,32}, wn in {0,64}; per wave 32x64 per mat.
// ---------------------------------------------------------------------------
__global__ __launch_bounds__(256, 1)
void gemm_xv(const float* __restrict__ X, const float* __restrict__ Vx,
             const float* __restrict__ Vd, short* __restrict__ xvb) {
    constexpr int PADK = 40;            // proven conflict-free LDS row pitch
    __shared__ short As[64 * PADK];
    __shared__ short Bs[2][128 * PADK];

    const int m0 = blockIdx.x * 64;
    const int tid = threadIdx.x;
    const int wave = tid >> 6;
    const int lane = tid & 63;
    const int lr = lane & 15;
    const int q  = lane >> 4;
    const int wm = (wave >> 1) * 32;
    const int wn = (wave & 1) * 64;

    floatx4 acc[2][2][4] = {};          // [mat][mi][nj]

    for (int k0 = 0; k0 < DIMN; k0 += 32) {
        // A: 64x32 fp32 -> bf16 LDS (512 float4, 2/thread)
        #pragma unroll
        for (int i = 0; i < 2; ++i) {
            int f = tid + i * 256;
            int r = f >> 3, c = (f & 7) * 4;
            float4 v = *(const float4*)(X + (size_t)(m0 + r) * DIMN + k0 + c);
            *(short4*)&As[r * PADK + c] =
                make_short4(f2bf(v.x), f2bf(v.y), f2bf(v.z), f2bf(v.w));
        }
        // B: two 128x32 tiles (V_x, V_d), 1024 float4 each, 4/thread each
        #pragma unroll
        for (int i = 0; i < 4; ++i) {
            int f = tid + i * 256;
            int r = f >> 3, c = (f & 7) * 4;
            float4 v = *(const float4*)(Vx + (size_t)r * DIMN + k0 + c);
            *(short4*)&Bs[0][r * PADK + c] =
                make_short4(f2bf(v.x), f2bf(v.y), f2bf(v.z), f2bf(v.w));
            float4 w = *(const float4*)(Vd + (size_t)r * DIMN + k0 + c);
            *(short4*)&Bs[1][r * PADK + c] =
                make_short4(f2bf(w.x), f2bf(w.y), f2bf(w.z), f2bf(w.w));
        }
        __syncthreads();

        short8 af[2], bfr[2][4];
        #pragma unroll
        for (int mi = 0; mi < 2; ++mi)
            af[mi] = *(const short8*)&As[(wm + mi * 16 + lr) * PADK + q * 8];
        #pragma unroll
        for (int mat = 0; mat < 2; ++mat)
            #pragma unroll
            for (int nj = 0; nj < 4; ++nj)
                bfr[mat][nj] = *(const short8*)&Bs[mat][(wn + nj * 16 + lr) * PADK + q * 8];

        #pragma unroll
        for (int mat = 0; mat < 2; ++mat)
            #pragma unroll
            for (int mi = 0; mi < 2; ++mi)
                #pragma unroll
                for (int nj = 0; nj < 4; ++nj)
                    acc[mat][mi][nj] = __builtin_amdgcn_mfma_f32_16x16x32_bf16(
                        af[mi], bfr[mat][nj], acc[mat][mi][nj], 0, 0, 0);
        __syncthreads();
    }

    // Epilogue: C/D layout col=lane&15, row=(lane>>4)*4+reg (m89-verified).
    #pragma unroll
    for (int mat = 0; mat < 2; ++mat)
        #pragma unroll
        for (int mi = 0; mi < 2; ++mi)
            #pragma unroll
            for (int nj = 0; nj < 4; ++nj)
                #pragma unroll
                for (int r = 0; r < 4; ++r) {
                    int row = m0 + wm + mi * 16 + q * 4 + r;
                    int col = wn + nj * 16 + lr;
                    xvb[(size_t)row * 256 + mat * RANKN + col] =
                        f2bf(acc[mat][mi][nj][r]);
                }
}

// ---------------------------------------------------------------------------
// Phase 2+3 fused: producer-consumer. Grid (16 d-chunks, 16 batches) = 256
// blocks = 1/CU. 256 threads = 4 waves (1/SIMD -> 512-VGPR budget).
//   waves 0,1 (producers): hold U_x/U_d fragments for this d-chunk in
//     registers (one-time load+convert); per 32-step chunk, MFMA
//     wx/wd[32][128] from bf16 xv into double-buffered LDS for chunk c+1
//     while consumers scan chunk c.
//   waves 2,3 (consumers): 128 scan chains (b, d0+cix). wx/wd from LDS with
//     depth-4 register prefetch; x from depth-16 register ring; 2 obligatory
//     HBM stores per step (obuf, hbuf).
// Barriers: both roles execute exactly 1 (prologue) + 32 (per-chunk) barriers
// in uniform control flow.
// ---------------------------------------------------------------------------
__global__ __launch_bounds__(256, 1)
void fused_scan(const short* __restrict__ xvb, const float* __restrict__ x,
                const float* __restrict__ h0,
                const float* __restrict__ Ux, const float* __restrict__ Ud,
                const float* __restrict__ r_h, const float* __restrict__ r_delta,
                const float* __restrict__ bvec, const float* __restrict__ b_delta,
                const float* __restrict__ b_gate,
                float* __restrict__ obuf, float* __restrict__ hbuf) {
    __shared__ float wxs[2][32][128];   // [buf][t-in-chunk][d-in-chunk]
    __shared__ float wds[2][32][128];   // 64 KiB total

    const int b   = blockIdx.y;         // 0..15
    const int d0  = blockIdx.x * 128;   // 0..1920
    const int tid = threadIdx.x;
    const int wave = tid >> 6;
    const int lane = tid & 63;
    const int lr = lane & 15;
    const int q  = lane >> 4;

    // producer geometry
    const int wn = (wave & 1) * 64;     // waves 0,1 -> n-halves 0,64
    // consumer geometry
    const int cix = tid & 127;          // waves 2,3 -> chain 0..127
    const int d   = d0 + cix;
    const size_t xoff = (size_t)b * DIMN + (size_t)d;   // [B,D]-slab offset

    short8 uf[2][4][4];                 // [mat][nj][ks] U fragments (producer)
    float h = 0.f, rh = 0.f, rd = 0.f, bb = 0.f, bdl = 0.f, bg = 0.f;
    float xb[16];                       // consumer x ring, 16 steps deep
    float wxp[4], wdp[4];               // consumer LDS prefetch, 4 deep

    // Producer: compute wx/wd for `chunk` into LDS buffer pb.
    // MFMA conventions identical to gemm_xv (A/B: lane=(row lr, k q*8..);
    // C: col=lane&15, row=(lane>>4)*4+reg).
    auto fill = [&](int chunk, int pb) {
        const int t0 = chunk * 32;
        short8 af[2][2][4];             // [mat][mi][ks], issue all loads first
        #pragma unroll
        for (int mat = 0; mat < 2; ++mat)
            #pragma unroll
            for (int mi = 0; mi < 2; ++mi) {
                const size_t row = (size_t)((t0 + mi * 16 + lr) * BBATCH + b);
                #pragma unroll
                for (int ks = 0; ks < 4; ++ks)
                    af[mat][mi][ks] = *(const short8*)
                        &xvb[row * 256 + mat * RANKN + ks * 32 + q * 8];
            }
        #pragma unroll
        for (int mat = 0; mat < 2; ++mat)
            #pragma unroll
            for (int mi = 0; mi < 2; ++mi)
                #pragma unroll
                for (int nj = 0; nj < 4; ++nj) {
                    floatx4 acc = {};
                    #pragma unroll
                    for (int ks = 0; ks < 4; ++ks)
                        acc = __builtin_amdgcn_mfma_f32_16x16x32_bf16(
                            af[mat][mi][ks], uf[mat][nj][ks], acc, 0, 0, 0);
                    float* outp = mat ? &wds[pb][0][0] : &wxs[pb][0][0];
                    #pragma unroll
                    for (int r = 0; r < 4; ++r)
                        outp[(mi * 16 + q * 4 + r) * 128 + wn + nj * 16 + lr]
                            = acc[r];
                }
    };

    if (wave < 2) {
        // one-time U fragment load (L2/L3), fp32 -> bf16
        #pragma unroll
        for (int mat = 0; mat < 2; ++mat) {
            const float* Up = mat ? Ud : Ux;
            #pragma unroll
            for (int nj = 0; nj < 4; ++nj) {
                const size_t dd = (size_t)(d0 + wn + nj * 16 + lr);
                #pragma unroll
                for (int ks = 0; ks < 4; ++ks) {
                    const int k = ks * 32 + q * 8;
                    float4 u0 = *(const float4*)&Up[dd * RANKN + k];
                    float4 u1 = *(const float4*)&Up[dd * RANKN + k + 4];
                    short8 v;
                    v[0] = f2bf(u0.x); v[1] = f2bf(u0.y);
                    v[2] = f2bf(u0.z); v[3] = f2bf(u0.w);
                    v[4] = f2bf(u1.x); v[5] = f2bf(u1.y);
                    v[6] = f2bf(u1.z); v[7] = f2bf(u1.w);
                    uf[mat][nj][ks] = v;
                }
            }
        }
        fill(0, 0);
    } else {
        rh  = r_h[d];  rd  = r_delta[d];
        bb  = bvec[d]; bdl = b_delta[d]; bg = b_gate[d];
        h = h0[xoff];
        hbuf[xoff] = h;                 // h[0] = h0
        #pragma unroll
        for (int p = 0; p < 16; ++p)
            xb[p] = x[(size_t)p * BD + xoff];
    }
    __syncthreads();
    if (wave >= 2) {
        #pragma unroll
        for (int s = 0; s < 4; ++s) {
            wxp[s] = wxs[0][s][cix];
            wdp[s] = wds[0][s][cix];
        }
    }

    for (int c = 0; c < 32; ++c) {
        if (wave < 2) {
            if (c < 31) fill(c + 1, (c + 1) & 1);
        } else {
            const int pb = c & 1;
            #pragma unroll
            for (int s = 0; s < 32; ++s) {
                const int t = c * 32 + s;
                const float wx = wxp[s & 3], wd = wdp[s & 3];
                if (s < 28) {           // depth-4 LDS prefetch
                    wxp[s & 3] = wxs[pb][s + 4][cix];
                    wdp[s & 3] = wds[pb][s + 4][cix];
                }
                const float xt = xb[s & 15];
                if (c < 31 || s < 16)   // == (t + 16 < TT)
                    xb[s & 15] = x[(size_t)(t + 16) * BD + xoff];

                const float cand  = fast_tanh(rh * h + wx + bb);
                const float delta = fast_sigmoid(wd + rd * h + bdl);
                h = (1.0f - delta) * h + delta * cand;
                const float gg = h + xt + bg;
                obuf[(size_t)t * BD + xoff] = h * (gg * fast_sigmoid(gg));
                hbuf[(size_t)(t + 1) * BD + xoff] = h;
            }
        }
        __syncthreads();
        if (wave >= 2 && c < 31) {
            const int nb = (c + 1) & 1;
            #pragma unroll
            for (int s = 0; s < 4; ++s) {
                wxp[s] = wxs[nb][s][cix];
                wdp[s] = wds[nb][s][cix];
            }
        }
    }
}

// ---------------------------------------------------------------------------
extern "C" void kernel_launch(void* const* d_in, const int* in_sizes, int n_in,
                              void* d_out, int out_size, void* d_ws, size_t ws_size,
                              hipStream_t stream) {
    const float* x       = (const float*)d_in[0];   // [T,B,D]
    const float* h0      = (const float*)d_in[1];   // [B,D]
    const float* U_x     = (const float*)d_in[2];   // [D,R]
    const float* V_x     = (const float*)d_in[3];   // [R,D]
    const float* U_d     = (const float*)d_in[4];   // [D,R]
    const float* V_d     = (const float*)d_in[5];   // [R,D]
    const float* r_h     = (const float*)d_in[6];
    const float* r_delta = (const float*)d_in[7];
    const float* bvec    = (const float*)d_in[8];
    const float* b_delta = (const float*)d_in[9];
    const float* b_gate  = (const float*)d_in[10];

    float* obuf = (float*)d_out;                    // output [T,B,D]
    float* hbuf = obuf + (size_t)TT * BD;           // h [T+1,B,D]
    short* xvb  = (short*)d_ws;                     // bf16 [16384][256]: xv|xd

    // Phase 1: both low-rank input projections, x read once, bf16 out.
    dim3 g1(TT * BBATCH / 64, 1, 1);                // 256 blocks
    gemm_xv<<<g1, 256, 0, stream>>>(x, V_x, V_d, xvb);

    // Phase 2+3: producer-consumer fused wx/wd GEMM + scan.
    dim3 g2(DIMN / 128, BBATCH, 1);                 // (16,16) = 256 blocks
    fused_scan<<<g2, 256, 0, stream>>>(xvb, x, h0, U_x, U_d,
                                       r_h, r_delta, bvec, b_delta, b_gate,
                                       obuf, hbuf);
}

// Round 2
// 550.059 us; speedup vs baseline: 1.4359x; 1.4359x over previous
//
#include <hip/hip_runtime.h>

#define DIMN 2048
#define RANKN 128
#define TT 1024
#define BBATCH 16
#define BD (BBATCH * DIMN)   // 32768 elements per timestep slice
#define CH 16                // scan chunk length (t-steps)
#define PADW 132             // LDS row pitch in floats (conflict-free)

typedef __attribute__((ext_vector_type(4))) float floatx4;
typedef __attribute__((ext_vector_type(8))) short short8;

// fp32 -> bf16 round-to-nearest-even on raw bits
__device__ __forceinline__ short f2bf(float f) {
    unsigned u = __float_as_uint(f);
    unsigned r = (u + 0x7FFFu + ((u >> 16) & 1u)) >> 16;
    return (short)r;
}
__device__ __forceinline__ float fast_sigmoid(float z) {
    return 1.0f / (1.0f + __expf(-z));
}
__device__ __forceinline__ float fast_tanh(float z) {
    return 1.0f - 2.0f / (__expf(2.0f * z) + 1.0f);
}

// ---------------------------------------------------------------------------
// Prep: V_x|V_d -> bf16 Vb[2][128][2048], one-time (kills per-block reconvert
// of V in gemm_xv: 512 blocks x ~100 VALU/iter of f2bf -> 0).
// ---------------------------------------------------------------------------
__global__ __launch_bounds__(256)
void prep_vb(const float* __restrict__ Vx, const float* __restrict__ Vd,
             short* __restrict__ Vb) {
    const int gid = blockIdx.x * 256 + threadIdx.x;     // 0..65535
    const size_t base = (size_t)gid * 8;
    const size_t half = (size_t)RANKN * DIMN;           // 262144
    const float* src = (base < half) ? Vx : Vd;
    const size_t off = (base < half) ? base : (base - half);
    float4 a = *(const float4*)(src + off);
    float4 c = *(const float4*)(src + off + 4);
    short8 v;
    v[0] = f2bf(a.x); v[1] = f2bf(a.y); v[2] = f2bf(a.z); v[3] = f2bf(a.w);
    v[4] = f2bf(c.x); v[5] = f2bf(c.y); v[6] = f2bf(c.z); v[7] = f2bf(c.w);
    *(short8*)(Vb + base) = v;
}

// ---------------------------------------------------------------------------
// Phase 1: xvb = x @ [V_x^T | V_d^T] as bf16 [16384][256].
// M-tile 32 -> 512 blocks = 2 blocks/CU (inter-block latency hiding; the old
// 256-block version was 1/CU and serialized on load latency every K-iter).
// 4 waves: wave -> (mat = wave>>1, n-half = (wave&1)*64); acc[2 mi][4 nj].
// Numerics identical to previous passing run (same f2bf points, same MFMA
// accumulation order over k0).
// ---------------------------------------------------------------------------
__global__ __launch_bounds__(256, 2)
void gemm_xv(const float* __restrict__ X, const short* __restrict__ Vb,
             short* __restrict__ xvb) {
    constexpr int PADK = 40;            // proven conflict-free (80 B, 16-B mult)
    __shared__ short As[32 * PADK];
    __shared__ short Bs[2][128 * PADK];

    const int m0 = blockIdx.x * 32;
    const int tid = threadIdx.x;
    const int wave = tid >> 6;
    const int lane = tid & 63;
    const int lr = lane & 15;
    const int q  = lane >> 4;
    const int mat = wave >> 1;
    const int wn  = (wave & 1) * 64;

    floatx4 acc[2][4] = {};

    for (int k0 = 0; k0 < DIMN; k0 += 32) {
        // A: 32x32 fp32 -> bf16 (1 float4/thread)
        {
            int r = tid >> 3, c = (tid & 7) * 4;
            float4 v = *(const float4*)(X + (size_t)(m0 + r) * DIMN + k0 + c);
            *(short4*)&As[r * PADK + c] =
                make_short4(f2bf(v.x), f2bf(v.y), f2bf(v.z), f2bf(v.w));
        }
        // B: 2x128x32 bf16 copied from pre-converted Vb (4 short8/thread)
        #pragma unroll
        for (int i = 0; i < 4; ++i) {
            int u = tid + i * 256;          // 0..1023
            int bm = u >> 9;
            int rem = u & 511;
            int r = rem >> 2, c8 = (rem & 3) * 8;
            short8 v = *(const short8*)(Vb + ((size_t)bm * RANKN + r) * DIMN + k0 + c8);
            *(short8*)&Bs[bm][r * PADK + c8] = v;
        }
        __syncthreads();

        short8 af[2], bfr[4];
        #pragma unroll
        for (int mi = 0; mi < 2; ++mi)
            af[mi] = *(const short8*)&As[(mi * 16 + lr) * PADK + q * 8];
        #pragma unroll
        for (int nj = 0; nj < 4; ++nj)
            bfr[nj] = *(const short8*)&Bs[mat][(wn + nj * 16 + lr) * PADK + q * 8];

        #pragma unroll
        for (int mi = 0; mi < 2; ++mi)
            #pragma unroll
            for (int nj = 0; nj < 4; ++nj)
                acc[mi][nj] = __builtin_amdgcn_mfma_f32_16x16x32_bf16(
                    af[mi], bfr[nj], acc[mi][nj], 0, 0, 0);
        __syncthreads();
    }

    // C/D layout: col=lane&15, row=(lane>>4)*4+reg (m89-verified)
    #pragma unroll
    for (int mi = 0; mi < 2; ++mi)
        #pragma unroll
        for (int nj = 0; nj < 4; ++nj)
            #pragma unroll
            for (int r = 0; r < 4; ++r) {
                int row = m0 + mi * 16 + q * 4 + r;
                int col = mat * RANKN + wn + nj * 16 + lr;
                xvb[(size_t)row * 256 + col] = f2bf(acc[mi][nj][r]);
            }
}

// ---------------------------------------------------------------------------
// Phase 2+3 fused, 3-stage pipeline. 256 blocks (XCD-swizzled so the 16
// blocks sharing batch b land on one XCD -> xvb b-slice L2-resident).
// Per iter i (i = 0..65, one barrier each):
//   waves 0,1 (producer+flusher):
//     - MFMA-fill wx/wd[chunk i] into LDS buf i&1 (U frags + xvb frags
//       register-prefetched one iter ahead -> no load wait before MFMA)
//     - prefetch x[chunk i-1] into regs (used next iter)
//     - flush chunk i-2: read h from LDS, compute out = h*silu(h+x+bg),
//       store obuf/hbuf as coalesced dwordx4
//   waves 2,3 (consumer): scan chunk i-1: 32 ds_read_b32 burst (wx,wd),
//     16-step pure-VALU h-chain, ds_write h. ZERO vmem in the serial loop ->
//     no vmcnt waits on the chain (the previous version's ~1000 cy/step
//     stall was store-retire serialization from conservative waits).
// Buffer parities: fill writes (i&1); consumer reads/writes (i-1)&1;
// flusher reads hs[(i-2)&1] = hs[i&1] -> all disjoint each iter.
// LDS: 3 arrays x 2 bufs x 16 x 132 floats = 50.7 KB.
// ---------------------------------------------------------------------------
__global__ __launch_bounds__(256, 1)
void fused_scan(const short* __restrict__ xvb, const float* __restrict__ x,
                const float* __restrict__ h0,
                const float* __restrict__ Ux, const float* __restrict__ Ud,
                const float* __restrict__ r_h, const float* __restrict__ r_delta,
                const float* __restrict__ bvec, const float* __restrict__ b_delta,
                const float* __restrict__ b_gate,
                float* __restrict__ obuf, float* __restrict__ hbuf) {
    __shared__ float wxs[2][CH * PADW];
    __shared__ float wds[2][CH * PADW];
    __shared__ float hs [2][CH * PADW];

    // XCD-aware decode: blocks with the same b share an XCD (2 b-slices of
    // xvb = 1 MB -> L2-resident fill reads).
    const int id   = blockIdx.x;
    const int xcd  = id & 7;
    const int slot = id >> 3;
    const int b  = xcd + 8 * (slot & 1);
    const int d0 = (slot >> 1) * 128;

    const int tid = threadIdx.x;
    const int wave = tid >> 6;
    const int lane = tid & 63;
    const int lr = lane & 15;
    const int q  = lane >> 4;
    const int wn = (wave & 1) * 64;     // producer n-half

    // consumer geometry
    const int cix = tid & 127;
    const int d   = d0 + cix;
    const size_t xoff = (size_t)b * DIMN + d;

    // flusher geometry (waves 0,1: fid = tid in 0..127)
    const int dq  = tid & 31;
    const int tof = (tid >> 5) & 3;
    const size_t xoffF = (size_t)b * DIMN + d0 + dq * 4;

    // producer state
    short8 uf[2][4][4];                 // U fragments [mat][nj][ks]
    short8 afp[2][4], afn[2][4];        // xvb A-frag double buffer
    float4 xpre[4], xnew[4];            // flusher x prefetch (one iter ahead)
    float4 bg4 = {};
    // consumer state
    float h = 0.f, rh = 0.f, rd = 0.f, bb = 0.f, bdl = 0.f;

    if (wave < 2) {
        // one-time U fragment load + convert (B-operand: lane holds col=lr,
        // k = ks*32 + q*8 .. +8)
        #pragma unroll
        for (int mat = 0; mat < 2; ++mat) {
            const float* Up = mat ? Ud : Ux;
            #pragma unroll
            for (int nj = 0; nj < 4; ++nj) {
                const size_t dd = (size_t)(d0 + wn + nj * 16 + lr);
                #pragma unroll
                for (int ks = 0; ks < 4; ++ks) {
                    const int k = ks * 32 + q * 8;
                    float4 u0 = *(const float4*)&Up[dd * RANKN + k];
                    float4 u1 = *(const float4*)&Up[dd * RANKN + k + 4];
                    short8 v;
                    v[0] = f2bf(u0.x); v[1] = f2bf(u0.y);
                    v[2] = f2bf(u0.z); v[3] = f2bf(u0.w);
                    v[4] = f2bf(u1.x); v[5] = f2bf(u1.y);
                    v[6] = f2bf(u1.z); v[7] = f2bf(u1.w);
                    uf[mat][nj][ks] = v;
                }
            }
        }
        // prefetch xvb fragments for chunk 0
        {
            const size_t row = (size_t)lr * BBATCH + b;     // t = 0 + lr
            #pragma unroll
            for (int mat = 0; mat < 2; ++mat)
                #pragma unroll
                for (int ks = 0; ks < 4; ++ks)
                    afp[mat][ks] = *(const short8*)
                        &xvb[row * 256 + mat * RANKN + ks * 32 + q * 8];
        }
        bg4 = *(const float4*)&b_gate[d0 + dq * 4];
    } else {
        rh  = r_h[d];  rd  = r_delta[d];
        bb  = bvec[d]; bdl = b_delta[d];
        h = h0[xoff];
        hbuf[xoff] = h;                 // h[0] = h0
    }

    for (int i = 0; i < 66; ++i) {
        if (wave < 2) {
            // ---- fill chunk i (MFMA on prefetched frags, zero load wait)
            if (i < 64) {
                const int pb = i & 1;
                #pragma unroll
                for (int mat = 0; mat < 2; ++mat) {
                    float* outp = mat ? wds[pb] : wxs[pb];
                    #pragma unroll
                    for (int nj = 0; nj < 4; ++nj) {
                        floatx4 acc = {};
                        #pragma unroll
                        for (int ks = 0; ks < 4; ++ks)
                            acc = __builtin_amdgcn_mfma_f32_16x16x32_bf16(
                                afp[mat][ks], uf[mat][nj][ks], acc, 0, 0, 0);
                        // C: row=q*4+r = t-in-chunk, col = output d
                        #pragma unroll
                        for (int r = 0; r < 4; ++r)
                            outp[(q * 4 + r) * PADW + wn + nj * 16 + lr] = acc[r];
                    }
                }
            }
            // ---- prefetch xvb frags for chunk i+1
            if (i < 63) {
                const size_t row = (size_t)((i + 1) * CH + lr) * BBATCH + b;
                #pragma unroll
                for (int mat = 0; mat < 2; ++mat)
                    #pragma unroll
                    for (int ks = 0; ks < 4; ++ks)
                        afn[mat][ks] = *(const short8*)
                            &xvb[row * 256 + mat * RANKN + ks * 32 + q * 8];
            }
            // ---- prefetch x for chunk i-1 (flushed NEXT iter)
            if (i >= 1 && i < 65) {
                const int tb = (i - 1) * CH;
                #pragma unroll
                for (int jj = 0; jj < 4; ++jj)
                    xnew[jj] = *(const float4*)
                        &x[(size_t)(tb + jj * 4 + tof) * BD + xoffF];
            }
            // ---- flush chunk i-2: out = h*silu(h+x+bg), copy h to hbuf
            if (i >= 2) {
                const int j = i - 2;
                const int fb = j & 1;
                const int tb = j * CH;
                #pragma unroll
                for (int jj = 0; jj < 4; ++jj) {
                    const int t = jj * 4 + tof;
                    const float4 hv = *(const float4*)&hs[fb][t * PADW + dq * 4];
                    const float4 xv = xpre[jj];
                    float4 ov;
                    {
                        float g0 = hv.x + xv.x + bg4.x;
                        ov.x = hv.x * (g0 * fast_sigmoid(g0));
                        float g1 = hv.y + xv.y + bg4.y;
                        ov.y = hv.y * (g1 * fast_sigmoid(g1));
                        float g2 = hv.z + xv.z + bg4.z;
                        ov.z = hv.z * (g2 * fast_sigmoid(g2));
                        float g3 = hv.w + xv.w + bg4.w;
                        ov.w = hv.w * (g3 * fast_sigmoid(g3));
                    }
                    *(float4*)&obuf[(size_t)(tb + t) * BD + xoffF] = ov;
                    *(float4*)&hbuf[(size_t)(tb + t + 1) * BD + xoffF] = hv;
                }
            }
            // ---- rotate prefetch registers
            if (i < 63) {
                #pragma unroll
                for (int mat = 0; mat < 2; ++mat)
                    #pragma unroll
                    for (int ks = 0; ks < 4; ++ks)
                        afp[mat][ks] = afn[mat][ks];
            }
            if (i >= 1 && i < 65) {
                #pragma unroll
                for (int jj = 0; jj < 4; ++jj)
                    xpre[jj] = xnew[jj];
            }
        } else if (i >= 1 && i < 65) {
            // ---- consumer: scan chunk i-1 (pure VALU + LDS; no vmem)
            const int pb = (i - 1) & 1;
            float wxr[CH], wdr[CH];
            #pragma unroll
            for (int s = 0; s < CH; ++s) {
                wxr[s] = wxs[pb][s * PADW + cix];
                wdr[s] = wds[pb][s * PADW + cix];
            }
            #pragma unroll
            for (int s = 0; s < CH; ++s) {
                const float cand  = fast_tanh(rh * h + wxr[s] + bb);
                const float delta = fast_sigmoid(wdr[s] + rd * h + bdl);
                h = (1.0f - delta) * h + delta * cand;
                hs[pb][s * PADW + cix] = h;
            }
        }
        __syncthreads();
    }
}

// ---------------------------------------------------------------------------
extern "C" void kernel_launch(void* const* d_in, const int* in_sizes, int n_in,
                              void* d_out, int out_size, void* d_ws, size_t ws_size,
                              hipStream_t stream) {
    const float* x       = (const float*)d_in[0];   // [T,B,D]
    const float* h0      = (const float*)d_in[1];   // [B,D]
    const float* U_x     = (const float*)d_in[2];   // [D,R]
    const float* V_x     = (const float*)d_in[3];   // [R,D]
    const float* U_d     = (const float*)d_in[4];   // [D,R]
    const float* V_d     = (const float*)d_in[5];   // [R,D]
    const float* r_h     = (const float*)d_in[6];
    const float* r_delta = (const float*)d_in[7];
    const float* bvec    = (const float*)d_in[8];
    const float* b_delta = (const float*)d_in[9];
    const float* b_gate  = (const float*)d_in[10];

    float* obuf = (float*)d_out;                    // output [T,B,D]
    float* hbuf = obuf + (size_t)TT * BD;           // h [T+1,B,D]
    short* xvb  = (short*)d_ws;                     // bf16 [16384][256]: xv|xd
    short* Vb   = xvb + (size_t)TT * BBATCH * 256;  // bf16 [2][128][2048]

    // Phase 0: one-time V -> bf16
    prep_vb<<<256, 256, 0, stream>>>(V_x, V_d, Vb);

    // Phase 1: both low-rank projections, x read once, bf16 out. 2 blocks/CU.
    gemm_xv<<<TT * BBATCH / 32, 256, 0, stream>>>(x, Vb, xvb);

    // Phase 2+3: producer/consumer/flusher fused GEMM + scan + gate.
    fused_scan<<<256, 256, 0, stream>>>(xvb, x, h0, U_x, U_d,
                                        r_h, r_delta, bvec, b_delta, b_gate,
                                        obuf, hbuf);
}